// Round 18
// baseline (529.504 us; speedup 1.0000x reference)
//
#include <hip/hip_runtime.h>
#include <hip/hip_fp16.h>
#include <hip/hip_cooperative_groups.h>
#include <math.h>

namespace cg = cooperative_groups;

#define Nn 10000
#define Ee 320000
#define EE 330000        // E + N self loops
#define EEPS 400080      // pad-8 capacity
#define INF_ 256
#define NH 4
#define OUTC 128
#define F1 512
#define F2 512
#define SLOPE 0.2f
#define NB 40            // ceil(Nn/256)
#define CAP 64           // LDS edge cache per node (P(deg>63) ~ 6e-8; overflow path covers)
#define CGRID 512        // cooperative grid (2 blocks/CU, always co-resident)

static __device__ __forceinline__ float lrelu(float x) { return fmaxf(x, SLOPE * x); }

using frag_ab = __attribute__((ext_vector_type(8))) _Float16;
using frag_c  = __attribute__((ext_vector_type(4))) float;

// ---------------- cooperative prep: zero+convert -> count -> scan -> scatter ----------------
__global__ __launch_bounds__(256) void coop_prep(const int* __restrict__ ei,
                                                 const float* __restrict__ x,
                                                 const float* __restrict__ W1,
                                                 const float* __restrict__ W2,
                                                 int* counts, int* blocksums,
                                                 int* poffsets, int* cursor,
                                                 int* __restrict__ csr,
                                                 _Float16* __restrict__ xh,
                                                 _Float16* __restrict__ w1t,
                                                 _Float16* __restrict__ w2t) {
    __shared__ int sd[256];
    cg::grid_group grid = cg::this_grid();
    const int T = CGRID * 256;
    int tid = blockIdx.x * 256 + threadIdx.x;

    // phase 0: zero counts + fp16 conversions (independent work)
    for (int i = tid; i < Nn; i += T) counts[i] = 0;
    for (int i = tid; i < Nn * INF_ / 4; i += T) {
        float4 v = *(const float4*)(x + (size_t)i * 4);
        _Float16 oh[4] = {(_Float16)v.x, (_Float16)v.y, (_Float16)v.z, (_Float16)v.w};
        *(float2*)(xh + (size_t)i * 4) = *(float2*)oh;
    }
    for (int i = tid; i < INF_ * F1; i += T) {
        int n = i >> 8, k = i & 255;                       // w1t[n][k], n<512, k<256
        w1t[i] = (_Float16)W1[(size_t)k * F1 + n];
    }
    for (int i = tid; i < F1 * F2; i += T) {
        int n = i >> 9, k = i & 511;                       // w2t[n][k], n<512, k<512
        w2t[i] = (_Float16)W2[(size_t)k * F2 + n];
    }
    grid.sync();

    // phase 1: count in-degrees
    for (int e = tid; e < Ee; e += T) atomicAdd(&counts[ei[Ee + e]], 1);
    grid.sync();

    // phase 2: per-block inclusive scan of padded counts (blocks 0..39)
    if (blockIdx.x < NB) {
        int t = threadIdx.x, i = blockIdx.x * 256 + t;
        int v = (i < Nn) ? ((counts[i] + 8) & ~7) : 0;     // +1 self loop, pad-8
        sd[t] = v;
        __syncthreads();
        int xx = v;
        for (int off = 1; off < 256; off <<= 1) {
            int u = (t >= off) ? sd[t - off] : 0;
            __syncthreads();
            xx += u;
            sd[t] = xx;
            __syncthreads();
        }
        if (i < Nn) poffsets[i] = xx;                      // local inclusive (temp)
        if (t == 255) blocksums[blockIdx.x] = xx;
    }
    grid.sync();

    // phase 3: exclusive scan of the 40 block sums
    if (blockIdx.x == 0 && threadIdx.x < 64) {
        int t = threadIdx.x;
        int orig = (t < NB) ? blocksums[t] : 0;
        int v = orig;
        for (int off = 1; off < 64; off <<= 1) {
            int u = __shfl_up(v, off);
            if (t >= off) v += u;
        }
        if (t < NB) blocksums[t] = v - orig;
    }
    grid.sync();

    // phase 4: finalize poffsets/cursor
    if (blockIdx.x < NB) {
        int t = threadIdx.x, i = blockIdx.x * 256 + t;
        if (i < Nn) {
            int v = (counts[i] + 8) & ~7;
            int incl = poffsets[i];
            int base = blocksums[blockIdx.x];
            int e = base + incl - v;
            poffsets[i] = e;
            cursor[i] = e;
            if (i == Nn - 1) poffsets[Nn] = base + incl;
        }
    }
    grid.sync();

    // phase 5: scatter (self loops appended)
    for (int e = tid; e < EE; e += T) {
        int src, dst;
        if (e < Ee) { src = ei[e]; dst = ei[Ee + e]; }
        else        { src = e - Ee; dst = e - Ee; }
        int pos = atomicAdd(&cursor[dst], 1);
        csr[pos] = src;
    }
}

// ---------------- MFMA fp16 GEMM + fused alpha dots ----------------
#define LDK 40
__global__ __launch_bounds__(256) void mfma_gemm(const _Float16* __restrict__ A,
                                                 const _Float16* __restrict__ BT,
                                                 _Float16* __restrict__ C,
                                                 const float* __restrict__ a_src,
                                                 const float* __restrict__ a_dst,
                                                 float* __restrict__ as_out,
                                                 float* __restrict__ ad_out,
                                                 int M, int K) {
    __shared__ _Float16 As[64 * LDK];
    __shared__ _Float16 Bs[128 * LDK];
    const int tid = threadIdx.x;
    const int wave = tid >> 6, lane = tid & 63;
    const int q = lane >> 4, ml = lane & 15;
    const int bm = blockIdx.x * 64, bn = blockIdx.y * 128;
    const int head = blockIdx.y;
    const int srow = tid >> 2, scol = (tid & 3) * 8;

    frag_c acc[8];
#pragma unroll
    for (int f = 0; f < 8; f++)
#pragma unroll
        for (int r = 0; r < 4; r++) acc[f][r] = 0.f;

    for (int k0 = 0; k0 < K; k0 += 32) {
        int gm = bm + srow;
        frag_ab av;
        if (gm < M) av = *(const frag_ab*)(A + (size_t)gm * K + k0 + scol);
        else {
#pragma unroll
            for (int j = 0; j < 8; j++) av[j] = (_Float16)0.f;
        }
        *(frag_ab*)&As[srow * LDK + scol] = av;
        *(frag_ab*)&Bs[srow * LDK + scol] =
            *(const frag_ab*)(BT + (size_t)(bn + srow) * K + k0 + scol);
        *(frag_ab*)&Bs[(64 + srow) * LDK + scol] =
            *(const frag_ab*)(BT + (size_t)(bn + 64 + srow) * K + k0 + scol);
        __syncthreads();
        frag_ab a = *(frag_ab*)&As[(wave * 16 + ml) * LDK + q * 8];
#pragma unroll
        for (int f = 0; f < 8; f++) {
            frag_ab b = *(frag_ab*)&Bs[(f * 16 + ml) * LDK + q * 8];
            acc[f] = __builtin_amdgcn_mfma_f32_16x16x32_f16(a, b, acc[f], 0, 0, 0);
        }
        __syncthreads();
    }
    float asum[4] = {}, dsum[4] = {};
#pragma unroll
    for (int f = 0; f < 8; f++) {
        int cl = f * 16 + ml;
        int col = bn + cl;
        float sa = a_src[head * 128 + cl];
        float da = a_dst[head * 128 + cl];
#pragma unroll
        for (int r = 0; r < 4; r++) {
            int row = bm + wave * 16 + q * 4 + r;
            if (row < M) C[(size_t)row * (NH * 128) + col] = (_Float16)acc[f][r];
            asum[r] += acc[f][r] * sa;
            dsum[r] += acc[f][r] * da;
        }
    }
#pragma unroll
    for (int r = 0; r < 4; r++) {
#pragma unroll
        for (int off = 1; off < 16; off <<= 1) {
            asum[r] += __shfl_xor(asum[r], off);
            dsum[r] += __shfl_xor(dsum[r], off);
        }
    }
    if (ml == 0) {
#pragma unroll
        for (int r = 0; r < 4; r++) {
            int row = bm + wave * 16 + q * 4 + r;
            if (row < M) {
                as_out[row * NH + head] = asum[r];
                ad_out[row * NH + head] = dsum[r];
            }
        }
    }
}

// ---------------- fused softmax + aggregation, layer 1 (round-15 structure) ----------------
__global__ __launch_bounds__(256) void passAB1(const int* __restrict__ poffsets,
                                               const int* __restrict__ ends,
                                               const int* __restrict__ csr,
                                               const float* __restrict__ as,
                                               const float* __restrict__ ad,
                                               const _Float16* __restrict__ hh,
                                               const float* __restrict__ b1,
                                               _Float16* __restrict__ agg) {
    __shared__ int2 ew[16][CAP + 1];
    int head = blockIdx.x & 3;
    int qw = threadIdx.x >> 4;
    int l = threadIdx.x & 15;
    int n = (blockIdx.x >> 2) * 16 + qw;
    int pstart = poffsets[n], pend = poffsets[n + 1];
    int deg = ends[n] - pstart;
    int pdeg = pend - pstart;
    float adh = ad[n * NH + head];
    float m = -1e30f;
    for (int k = l; k < deg; k += 16) {
        int src = csr[pstart + k];
        m = fmaxf(m, lrelu(as[src * NH + head] + adh));
    }
    m = fmaxf(m, __shfl_xor(m, 1));
    m = fmaxf(m, __shfl_xor(m, 2));
    m = fmaxf(m, __shfl_xor(m, 4));
    m = fmaxf(m, __shfl_xor(m, 8));
    float s = 0.f;
    for (int k = l; k < pdeg; k += 16) {
        int src = 0;
        float e = 0.f;
        if (k < deg) {
            src = csr[pstart + k];
            e = __expf(lrelu(as[src * NH + head] + adh) - m);
        }
        if (k < CAP) ew[qw][k] = make_int2(src, __float_as_int(e));
        s += e;
    }
    s += __shfl_xor(s, 1);
    s += __shfl_xor(s, 2);
    s += __shfl_xor(s, 4);
    s += __shfl_xor(s, 8);
    float inv = 1.f / (s + 1e-16f);
    __syncthreads();
    int c = head * 128 + (l << 3);
    float acc[8] = {};
    int lim = pdeg < CAP ? pdeg : CAP;
    for (int kk = 0; kk < lim; kk += 8) {
        int2 p[8];
#pragma unroll
        for (int j = 0; j < 8; j++) p[j] = ew[qw][kk + j];
#pragma unroll
        for (int j = 0; j < 8; j++) {
            float w = __int_as_float(p[j].y);
            frag_ab r = *(const frag_ab*)(hh + (size_t)p[j].x * F1 + c);
#pragma unroll
            for (int u = 0; u < 8; u++) acc[u] = fmaf((float)r[u], w, acc[u]);
        }
    }
    for (int kk = CAP; kk < pdeg; kk += 8) {   // ~never taken (P(deg>63)~6e-8)
#pragma unroll
        for (int j = 0; j < 8; j++) {
            int k = kk + j;
            int src = 0;
            float e = 0.f;
            if (k < deg) {
                src = csr[pstart + k];
                e = __expf(lrelu(as[src * NH + head] + adh) - m);
            }
            frag_ab r = *(const frag_ab*)(hh + (size_t)src * F1 + c);
#pragma unroll
            for (int u = 0; u < 8; u++) acc[u] = fmaf((float)r[u], e, acc[u]);
        }
    }
    _Float16 oh[8];
#pragma unroll
    for (int j = 0; j < 8; j++)
        oh[j] = (_Float16)fmaxf(acc[j] * inv + b1[c + j], 0.f);
    *(float4*)&agg[(size_t)n * F1 + c] = *(float4*)oh;
}

// ---------------- fused softmax + aggregation, layer 2 -> fp16 tmp ----------------
__global__ __launch_bounds__(256) void passAB2(const int* __restrict__ poffsets,
                                               const int* __restrict__ ends,
                                               const int* __restrict__ csr,
                                               const float* __restrict__ as,
                                               const float* __restrict__ ad,
                                               const _Float16* __restrict__ hh,
                                               _Float16* __restrict__ tmp) {
    __shared__ int2 ew[16][CAP + 1];
    int head = blockIdx.x & 3;
    int qw = threadIdx.x >> 4;
    int l = threadIdx.x & 15;
    int n = (blockIdx.x >> 2) * 16 + qw;
    int pstart = poffsets[n], pend = poffsets[n + 1];
    int deg = ends[n] - pstart;
    int pdeg = pend - pstart;
    float adh = ad[n * NH + head];
    float m = -1e30f;
    for (int k = l; k < deg; k += 16) {
        int src = csr[pstart + k];
        m = fmaxf(m, lrelu(as[src * NH + head] + adh));
    }
    m = fmaxf(m, __shfl_xor(m, 1));
    m = fmaxf(m, __shfl_xor(m, 2));
    m = fmaxf(m, __shfl_xor(m, 4));
    m = fmaxf(m, __shfl_xor(m, 8));
    float s = 0.f;
    for (int k = l; k < pdeg; k += 16) {
        int src = 0;
        float e = 0.f;
        if (k < deg) {
            src = csr[pstart + k];
            e = __expf(lrelu(as[src * NH + head] + adh) - m);
        }
        if (k < CAP) ew[qw][k] = make_int2(src, __float_as_int(e));
        s += e;
    }
    s += __shfl_xor(s, 1);
    s += __shfl_xor(s, 2);
    s += __shfl_xor(s, 4);
    s += __shfl_xor(s, 8);
    float inv = 1.f / (s + 1e-16f);
    __syncthreads();
    int c = head * 128 + (l << 3);
    float acc[8] = {};
    int lim = pdeg < CAP ? pdeg : CAP;
    for (int kk = 0; kk < lim; kk += 8) {
        int2 p[8];
#pragma unroll
        for (int j = 0; j < 8; j++) p[j] = ew[qw][kk + j];
#pragma unroll
        for (int j = 0; j < 8; j++) {
            float w = __int_as_float(p[j].y);
            frag_ab r = *(const frag_ab*)(hh + (size_t)p[j].x * F2 + c);
#pragma unroll
            for (int u = 0; u < 8; u++) acc[u] = fmaf((float)r[u], w, acc[u]);
        }
    }
    for (int kk = CAP; kk < pdeg; kk += 8) {
#pragma unroll
        for (int j = 0; j < 8; j++) {
            int k = kk + j;
            int src = 0;
            float e = 0.f;
            if (k < deg) {
                src = csr[pstart + k];
                e = __expf(lrelu(as[src * NH + head] + adh) - m);
            }
            frag_ab r = *(const frag_ab*)(hh + (size_t)src * F2 + c);
#pragma unroll
            for (int u = 0; u < 8; u++) acc[u] = fmaf((float)r[u], e, acc[u]);
        }
    }
    float qq = 0.25f * inv;
    _Float16 oh[8];
#pragma unroll
    for (int j = 0; j < 8; j++) oh[j] = (_Float16)(acc[j] * qq);
    *(float4*)&tmp[(size_t)n * F2 + c] = *(float4*)oh;   // [n][head*128+ch], fp16
}

// ---------------- reduce 4 heads + bias -> d_out (fp16 tmp [n][head][128]) ----------------
__global__ void reduce4(const _Float16* __restrict__ tmp, const float* __restrict__ b2,
                        float* __restrict__ out) {
    int i = blockIdx.x * 256 + threadIdx.x;
    if (i >= Nn * OUTC) return;
    int n = i >> 7, oc = i & 127;
    const _Float16* tp = tmp + (size_t)n * 512 + oc;
    out[i] = (float)tp[0] + (float)tp[128] + (float)tp[256] + (float)tp[384] + b2[oc];
}

extern "C" void kernel_launch(void* const* d_in, const int* in_sizes, int n_in,
                              void* d_out, int out_size, void* d_ws, size_t ws_size,
                              hipStream_t stream) {
    const int*   ei     = (const int*)d_in[1];
    const float* x      = (const float*)d_in[0];
    const float* W1     = (const float*)d_in[2];
    const float* a_src1 = (const float*)d_in[3];
    const float* a_dst1 = (const float*)d_in[4];
    const float* b1     = (const float*)d_in[5];
    const float* W2     = (const float*)d_in[6];
    const float* a_src2 = (const float*)d_in[7];
    const float* a_dst2 = (const float*)d_in[8];
    const float* b2     = (const float*)d_in[9];
    float* out = (float*)d_out;

    const size_t NF = (size_t)Nn * F1;
    float* f = (float*)d_ws;
    _Float16* tmp = (_Float16*)f;        // NF halves
    float* as1   = f + NF;
    float* ad1   = as1 + Nn * NH;
    float* as2   = ad1 + Nn * NH;
    float* ad2   = as2 + Nn * NH;
    int* csr     = (int*)(ad2 + Nn * NH);            // EEPS ints (pad-8)
    _Float16* hh   = (_Float16*)(csr + EEPS);
    _Float16* aggh = hh + NF;
    _Float16* xh   = aggh + NF;
    _Float16* w1t  = xh + (size_t)Nn * INF_;
    _Float16* w2t  = w1t + (size_t)F1 * INF_;
    int* counts    = (int*)(w2t + (size_t)F2 * F1);
    int* poffsets  = counts + Nn;
    int* cursor    = poffsets + Nn + 1;
    int* blocksums = cursor + Nn;

    // cooperative: zero+convert -> count -> scan -> scatter (one launch)
    {
        void* args[] = {(void*)&ei, (void*)&x, (void*)&W1, (void*)&W2,
                        (void*)&counts, (void*)&blocksums, (void*)&poffsets,
                        (void*)&cursor, (void*)&csr,
                        (void*)&xh, (void*)&w1t, (void*)&w2t};
        (void)hipLaunchCooperativeKernel((const void*)coop_prep, dim3(CGRID), dim3(256),
                                         args, 0, stream);
    }

    // Layer 1
    mfma_gemm<<<dim3((Nn + 63) / 64, F1 / 128), 256, 0, stream>>>(
        xh, w1t, hh, a_src1, a_dst1, as1, ad1, Nn, INF_);
    passAB1<<<(Nn / 16) * 4, 256, 0, stream>>>(poffsets, cursor, csr, as1, ad1, hh, b1, aggh);

    // Layer 2
    mfma_gemm<<<dim3((Nn + 63) / 64, F2 / 128), 256, 0, stream>>>(
        aggh, w2t, hh, a_src2, a_dst2, as2, ad2, Nn, F1);
    passAB2<<<(Nn / 16) * 4, 256, 0, stream>>>(poffsets, cursor, csr, as2, ad2, hh, tmp);
    reduce4<<<(Nn * OUTC + 255) / 256, 256, 0, stream>>>(tmp, b2, out);
}

// Round 19
// 241.484 us; speedup vs baseline: 2.1927x; 2.1927x over previous
//
#include <hip/hip_runtime.h>
#include <hip/hip_fp16.h>
#include <math.h>

#define Nn 10000
#define Ee 320000
#define EE 330000        // E + N self loops
#define EEPS 400080      // pad-8 capacity
#define INF_ 256
#define NH 4
#define OUTC 128
#define F1 512
#define F2 512
#define SLOPE 0.2f
#define NB 40            // ceil(Nn/256)
#define CAP 64           // LDS edge cache per node (P(deg>63) ~ 6e-8; overflow path covers)

#define SC_BLOCKS 1290       // ceil(EE/256)
#define CONVX_BLOCKS 2500    // Nn*INF_/(256*4)  (float4-vectorized)
#define TW1_BLOCKS 512       // (F1/64)*(INF_/4)
#define TW2_BLOCKS 1024      // (F2/64)*(F1/4)

static __device__ __forceinline__ float lrelu(float x) { return fmaxf(x, SLOPE * x); }

using frag_ab = __attribute__((ext_vector_type(8))) _Float16;
using frag_c  = __attribute__((ext_vector_type(4))) float;

// ---------------- CSR build (counts zeroed by memset; self-loop = +1 in scan) ----------------
__global__ void count_edges(const int* __restrict__ ei, int* counts) {
    int e = blockIdx.x * 256 + threadIdx.x;
    if (e < Ee) atomicAdd(&counts[ei[Ee + e]], 1);
}

__global__ __launch_bounds__(256) void reduce_counts(const int* __restrict__ counts,
                                                     int* __restrict__ blocksums) {
    __shared__ int sd[256];
    int t = threadIdx.x, i = blockIdx.x * 256 + t;
    int v = (i < Nn) ? ((counts[i] + 8) & ~7) : 0;   // (+1 self loop, pad 8)
    sd[t] = v;
    __syncthreads();
    for (int off = 128; off > 0; off >>= 1) {
        if (t < off) sd[t] += sd[t + off];
        __syncthreads();
    }
    if (t == 0) blocksums[blockIdx.x] = sd[0];
}

// block scan + inline exclusive scan of the 40 raw blocksums (kills scan_sums launch)
__global__ __launch_bounds__(256) void scan_final(const int* __restrict__ counts,
                                                  const int* __restrict__ blocksums,
                                                  int* __restrict__ poffsets,
                                                  int* __restrict__ cursor) {
    __shared__ int sd[256];
    __shared__ int sbase;
    int t = threadIdx.x, i = blockIdx.x * 256 + t;
    if (t < 64) {
        int v = (t < NB) ? blocksums[t] : 0;
        for (int off = 1; off < 64; off <<= 1) {
            int u = __shfl_up(v, off);
            if (t >= off) v += u;
        }
        int base = (blockIdx.x == 0) ? 0 : __shfl(v, blockIdx.x - 1);
        if (t == 0) sbase = base;
    }
    int v = (i < Nn) ? ((counts[i] + 8) & ~7) : 0;
    sd[t] = v;
    __syncthreads();
    int x = v;
    for (int off = 1; off < 256; off <<= 1) {
        int u = (t >= off) ? sd[t - off] : 0;
        __syncthreads();
        x += u;
        sd[t] = x;
        __syncthreads();
    }
    int base = sbase;
    int e = base + x - v;
    if (i < Nn) {
        poffsets[i] = e;
        cursor[i] = e;
        if (i == Nn - 1) poffsets[Nn] = e + v;
    }
}

// ---------------- prep: scatter edges + fp16 conversions in one launch ----------------
__global__ void prep(const int* __restrict__ ei, int* cursor, int* __restrict__ csr,
                     const float* __restrict__ x, const float* __restrict__ W1,
                     const float* __restrict__ W2, _Float16* __restrict__ xh,
                     _Float16* __restrict__ w1t, _Float16* __restrict__ w2t) {
    int b = blockIdx.x, t = threadIdx.x;
    if (b < SC_BLOCKS) {
        int e = b * 256 + t;
        if (e < EE) {
            int src, dst;
            if (e < Ee) { src = ei[e]; dst = ei[Ee + e]; }
            else        { src = e - Ee; dst = e - Ee; }
            int pos = atomicAdd(&cursor[dst], 1);
            csr[pos] = src;
        }
    } else if (b < SC_BLOCKS + CONVX_BLOCKS) {
        int i = ((b - SC_BLOCKS) * 256 + t) * 4;
        float4 v = *(const float4*)(x + i);
        _Float16 oh[4];
        oh[0] = (_Float16)v.x; oh[1] = (_Float16)v.y;
        oh[2] = (_Float16)v.z; oh[3] = (_Float16)v.w;
        *(float2*)(xh + i) = *(float2*)oh;
    } else if (b < SC_BLOCKS + CONVX_BLOCKS + TW1_BLOCKS) {
        int bb = b - SC_BLOCKS - CONVX_BLOCKS;
        int n = (bb & 7) * 64 + (t & 63);
        int k = (bb >> 3) * 4 + (t >> 6);
        w1t[(size_t)n * INF_ + k] = (_Float16)W1[(size_t)k * F1 + n];
    } else {
        int bb = b - SC_BLOCKS - CONVX_BLOCKS - TW1_BLOCKS;
        int n = (bb & 7) * 64 + (t & 63);
        int k = (bb >> 3) * 4 + (t >> 6);
        w2t[(size_t)n * F1 + k] = (_Float16)W2[(size_t)k * F2 + n];
    }
}

// ---------------- MFMA fp16 GEMM + fused alpha dots ----------------
#define LDK 40
__global__ __launch_bounds__(256) void mfma_gemm(const _Float16* __restrict__ A,
                                                 const _Float16* __restrict__ BT,
                                                 _Float16* __restrict__ C,
                                                 const float* __restrict__ a_src,
                                                 const float* __restrict__ a_dst,
                                                 float* __restrict__ as_out,
                                                 float* __restrict__ ad_out,
                                                 int M, int K) {
    __shared__ _Float16 As[64 * LDK];
    __shared__ _Float16 Bs[128 * LDK];
    const int tid = threadIdx.x;
    const int wave = tid >> 6, lane = tid & 63;
    const int q = lane >> 4, ml = lane & 15;
    const int bm = blockIdx.x * 64, bn = blockIdx.y * 128;
    const int head = blockIdx.y;
    const int srow = tid >> 2, scol = (tid & 3) * 8;

    frag_c acc[8];
#pragma unroll
    for (int f = 0; f < 8; f++)
#pragma unroll
        for (int r = 0; r < 4; r++) acc[f][r] = 0.f;

    for (int k0 = 0; k0 < K; k0 += 32) {
        int gm = bm + srow;
        frag_ab av;
        if (gm < M) av = *(const frag_ab*)(A + (size_t)gm * K + k0 + scol);
        else {
#pragma unroll
            for (int j = 0; j < 8; j++) av[j] = (_Float16)0.f;
        }
        *(frag_ab*)&As[srow * LDK + scol] = av;
        *(frag_ab*)&Bs[srow * LDK + scol] =
            *(const frag_ab*)(BT + (size_t)(bn + srow) * K + k0 + scol);
        *(frag_ab*)&Bs[(64 + srow) * LDK + scol] =
            *(const frag_ab*)(BT + (size_t)(bn + 64 + srow) * K + k0 + scol);
        __syncthreads();
        frag_ab a = *(frag_ab*)&As[(wave * 16 + ml) * LDK + q * 8];
#pragma unroll
        for (int f = 0; f < 8; f++) {
            frag_ab b = *(frag_ab*)&Bs[(f * 16 + ml) * LDK + q * 8];
            acc[f] = __builtin_amdgcn_mfma_f32_16x16x32_f16(a, b, acc[f], 0, 0, 0);
        }
        __syncthreads();
    }
    float asum[4] = {}, dsum[4] = {};
#pragma unroll
    for (int f = 0; f < 8; f++) {
        int cl = f * 16 + ml;
        int col = bn + cl;
        float sa = a_src[head * 128 + cl];
        float da = a_dst[head * 128 + cl];
#pragma unroll
        for (int r = 0; r < 4; r++) {
            int row = bm + wave * 16 + q * 4 + r;
            if (row < M) C[(size_t)row * (NH * 128) + col] = (_Float16)acc[f][r];
            asum[r] += acc[f][r] * sa;
            dsum[r] += acc[f][r] * da;
        }
    }
#pragma unroll
    for (int r = 0; r < 4; r++) {
#pragma unroll
        for (int off = 1; off < 16; off <<= 1) {
            asum[r] += __shfl_xor(asum[r], off);
            dsum[r] += __shfl_xor(dsum[r], off);
        }
    }
    if (ml == 0) {
#pragma unroll
        for (int r = 0; r < 4; r++) {
            int row = bm + wave * 16 + q * 4 + r;
            if (row < M) {
                as_out[row * NH + head] = asum[r];
                ad_out[row * NH + head] = dsum[r];
            }
        }
    }
}

// ---------------- fused softmax + aggregation, layer 1 (round-15 structure) ----------------
// Block = 16 nodes x 1 head (head = blockIdx&3 -> XCD slice, 2.56 MB L2-resident).
// Quarter-wave = one node. Phase 1: per-head softmax -> LDS (CAP=64, padded rows).
// Phase 2: shuffle-free 8-edge-unroll aggregation from LDS; overflow recomputed.
__global__ __launch_bounds__(256) void passAB1(const int* __restrict__ poffsets,
                                               const int* __restrict__ ends,
                                               const int* __restrict__ csr,
                                               const float* __restrict__ as,
                                               const float* __restrict__ ad,
                                               const _Float16* __restrict__ hh,
                                               const float* __restrict__ b1,
                                               _Float16* __restrict__ agg) {
    __shared__ int2 ew[16][CAP + 1];
    int head = blockIdx.x & 3;
    int qw = threadIdx.x >> 4;
    int l = threadIdx.x & 15;
    int n = (blockIdx.x >> 2) * 16 + qw;
    int pstart = poffsets[n], pend = poffsets[n + 1];
    int deg = ends[n] - pstart;
    int pdeg = pend - pstart;
    float adh = ad[n * NH + head];
    float m = -1e30f;
    for (int k = l; k < deg; k += 16) {
        int src = csr[pstart + k];
        m = fmaxf(m, lrelu(as[src * NH + head] + adh));
    }
    m = fmaxf(m, __shfl_xor(m, 1));
    m = fmaxf(m, __shfl_xor(m, 2));
    m = fmaxf(m, __shfl_xor(m, 4));
    m = fmaxf(m, __shfl_xor(m, 8));
    float s = 0.f;
    for (int k = l; k < pdeg; k += 16) {
        int src = 0;
        float e = 0.f;
        if (k < deg) {
            src = csr[pstart + k];
            e = __expf(lrelu(as[src * NH + head] + adh) - m);
        }
        if (k < CAP) ew[qw][k] = make_int2(src, __float_as_int(e));
        s += e;
    }
    s += __shfl_xor(s, 1);
    s += __shfl_xor(s, 2);
    s += __shfl_xor(s, 4);
    s += __shfl_xor(s, 8);
    float inv = 1.f / (s + 1e-16f);
    __syncthreads();
    int c = head * 128 + (l << 3);
    float acc[8] = {};
    int lim = pdeg < CAP ? pdeg : CAP;
    for (int kk = 0; kk < lim; kk += 8) {
        int2 p[8];
#pragma unroll
        for (int j = 0; j < 8; j++) p[j] = ew[qw][kk + j];
#pragma unroll
        for (int j = 0; j < 8; j++) {
            float w = __int_as_float(p[j].y);
            frag_ab r = *(const frag_ab*)(hh + (size_t)p[j].x * F1 + c);
#pragma unroll
            for (int u = 0; u < 8; u++) acc[u] = fmaf((float)r[u], w, acc[u]);
        }
    }
    for (int kk = CAP; kk < pdeg; kk += 8) {   // ~never taken (P(deg>63)~6e-8)
#pragma unroll
        for (int j = 0; j < 8; j++) {
            int k = kk + j;
            int src = 0;
            float e = 0.f;
            if (k < deg) {
                src = csr[pstart + k];
                e = __expf(lrelu(as[src * NH + head] + adh) - m);
            }
            frag_ab r = *(const frag_ab*)(hh + (size_t)src * F1 + c);
#pragma unroll
            for (int u = 0; u < 8; u++) acc[u] = fmaf((float)r[u], e, acc[u]);
        }
    }
    _Float16 oh[8];
#pragma unroll
    for (int j = 0; j < 8; j++)
        oh[j] = (_Float16)fmaxf(acc[j] * inv + b1[c + j], 0.f);
    *(float4*)&agg[(size_t)n * F1 + c] = *(float4*)oh;
}

// ---------------- fused softmax + aggregation, layer 2 -> fp16 tmp ----------------
__global__ __launch_bounds__(256) void passAB2(const int* __restrict__ poffsets,
                                               const int* __restrict__ ends,
                                               const int* __restrict__ csr,
                                               const float* __restrict__ as,
                                               const float* __restrict__ ad,
                                               const _Float16* __restrict__ hh,
                                               _Float16* __restrict__ tmp) {
    __shared__ int2 ew[16][CAP + 1];
    int head = blockIdx.x & 3;
    int qw = threadIdx.x >> 4;
    int l = threadIdx.x & 15;
    int n = (blockIdx.x >> 2) * 16 + qw;
    int pstart = poffsets[n], pend = poffsets[n + 1];
    int deg = ends[n] - pstart;
    int pdeg = pend - pstart;
    float adh = ad[n * NH + head];
    float m = -1e30f;
    for (int k = l; k < deg; k += 16) {
        int src = csr[pstart + k];
        m = fmaxf(m, lrelu(as[src * NH + head] + adh));
    }
    m = fmaxf(m, __shfl_xor(m, 1));
    m = fmaxf(m, __shfl_xor(m, 2));
    m = fmaxf(m, __shfl_xor(m, 4));
    m = fmaxf(m, __shfl_xor(m, 8));
    float s = 0.f;
    for (int k = l; k < pdeg; k += 16) {
        int src = 0;
        float e = 0.f;
        if (k < deg) {
            src = csr[pstart + k];
            e = __expf(lrelu(as[src * NH + head] + adh) - m);
        }
        if (k < CAP) ew[qw][k] = make_int2(src, __float_as_int(e));
        s += e;
    }
    s += __shfl_xor(s, 1);
    s += __shfl_xor(s, 2);
    s += __shfl_xor(s, 4);
    s += __shfl_xor(s, 8);
    float inv = 1.f / (s + 1e-16f);
    __syncthreads();
    int c = head * 128 + (l << 3);
    float acc[8] = {};
    int lim = pdeg < CAP ? pdeg : CAP;
    for (int kk = 0; kk < lim; kk += 8) {
        int2 p[8];
#pragma unroll
        for (int j = 0; j < 8; j++) p[j] = ew[qw][kk + j];
#pragma unroll
        for (int j = 0; j < 8; j++) {
            float w = __int_as_float(p[j].y);
            frag_ab r = *(const frag_ab*)(hh + (size_t)p[j].x * F2 + c);
#pragma unroll
            for (int u = 0; u < 8; u++) acc[u] = fmaf((float)r[u], w, acc[u]);
        }
    }
    for (int kk = CAP; kk < pdeg; kk += 8) {
#pragma unroll
        for (int j = 0; j < 8; j++) {
            int k = kk + j;
            int src = 0;
            float e = 0.f;
            if (k < deg) {
                src = csr[pstart + k];
                e = __expf(lrelu(as[src * NH + head] + adh) - m);
            }
            frag_ab r = *(const frag_ab*)(hh + (size_t)src * F2 + c);
#pragma unroll
            for (int u = 0; u < 8; u++) acc[u] = fmaf((float)r[u], e, acc[u]);
        }
    }
    float qq = 0.25f * inv;
    _Float16 oh[8];
#pragma unroll
    for (int j = 0; j < 8; j++) oh[j] = (_Float16)(acc[j] * qq);
    *(float4*)&tmp[(size_t)n * F2 + c] = *(float4*)oh;   // [n][head*128+ch], fp16
}

// ---------------- reduce 4 heads + bias -> d_out (fp16 tmp [n][head][128]) ----------------
__global__ void reduce4(const _Float16* __restrict__ tmp, const float* __restrict__ b2,
                        float* __restrict__ out) {
    int i = blockIdx.x * 256 + threadIdx.x;
    if (i >= Nn * OUTC) return;
    int n = i >> 7, oc = i & 127;
    const _Float16* tp = tmp + (size_t)n * 512 + oc;
    out[i] = (float)tp[0] + (float)tp[128] + (float)tp[256] + (float)tp[384] + b2[oc];
}

extern "C" void kernel_launch(void* const* d_in, const int* in_sizes, int n_in,
                              void* d_out, int out_size, void* d_ws, size_t ws_size,
                              hipStream_t stream) {
    const float* x      = (const float*)d_in[0];
    const int*   ei     = (const int*)d_in[1];
    const float* W1     = (const float*)d_in[2];
    const float* a_src1 = (const float*)d_in[3];
    const float* a_dst1 = (const float*)d_in[4];
    const float* b1     = (const float*)d_in[5];
    const float* W2     = (const float*)d_in[6];
    const float* a_src2 = (const float*)d_in[7];
    const float* a_dst2 = (const float*)d_in[8];
    const float* b2     = (const float*)d_in[9];
    float* out = (float*)d_out;

    const size_t NF = (size_t)Nn * F1;
    float* f = (float*)d_ws;
    _Float16* tmp = (_Float16*)f;        // NF halves
    float* as1   = f + NF;
    float* ad1   = as1 + Nn * NH;
    float* as2   = ad1 + Nn * NH;
    float* ad2   = as2 + Nn * NH;
    int* csr     = (int*)(ad2 + Nn * NH);            // EEPS ints (pad-8)
    _Float16* hh   = (_Float16*)(csr + EEPS);
    _Float16* aggh = hh + NF;
    _Float16* xh   = aggh + NF;
    _Float16* w1t  = xh + (size_t)Nn * INF_;
    _Float16* w2t  = w1t + (size_t)F1 * INF_;
    int* counts    = (int*)(w2t + (size_t)F2 * F1);
    int* poffsets  = counts + Nn;
    int* cursor    = poffsets + Nn + 1;
    int* blocksums = cursor + Nn;

    // CSR build: memset counts, count edges, reduce, scan (+1 self loop, pad-8)
    (void)hipMemsetAsync(counts, 0, Nn * sizeof(int), stream);
    count_edges<<<(Ee + 255) / 256, 256, 0, stream>>>(ei, counts);
    reduce_counts<<<NB, 256, 0, stream>>>(counts, blocksums);
    scan_final<<<NB, 256, 0, stream>>>(counts, blocksums, poffsets, cursor);

    // scatter + fp16 conversions, one launch
    prep<<<SC_BLOCKS + CONVX_BLOCKS + TW1_BLOCKS + TW2_BLOCKS, 256, 0, stream>>>(
        ei, cursor, csr, x, W1, W2, xh, w1t, w2t);

    // Layer 1
    mfma_gemm<<<dim3((Nn + 63) / 64, F1 / 128), 256, 0, stream>>>(
        xh, w1t, hh, a_src1, a_dst1, as1, ad1, Nn, INF_);
    passAB1<<<(Nn / 16) * 4, 256, 0, stream>>>(poffsets, cursor, csr, as1, ad1, hh, b1, aggh);

    // Layer 2
    mfma_gemm<<<dim3((Nn + 63) / 64, F2 / 128), 256, 0, stream>>>(
        aggh, w2t, hh, a_src2, a_dst2, as2, ad2, Nn, F1);
    passAB2<<<(Nn / 16) * 4, 256, 0, stream>>>(poffsets, cursor, csr, as2, ad2, hh, tmp);
    reduce4<<<(Nn * OUTC + 255) / 256, 256, 0, stream>>>(tmp, b2, out);
}